// Round 3
// baseline (555.313 us; speedup 1.0000x reference)
//
#include <hip/hip_runtime.h>
#include <math.h>

#define NP 48   // 16 batch * 3 channels

// ---------------- extract normalized 1D kernel from provided 2D kernel ----------------
__global__ __launch_bounds__(64) void k_extract(const float* __restrict__ kern,
                                                float* __restrict__ k1) {
    __shared__ float row[11];
    int t = threadIdx.x;
    if (t < 11) row[t] = kern[5 * 11 + t];   // center row of the 11x11 kernel
    __syncthreads();
    if (t < 11) {
        float s = 0.f;
#pragma unroll
        for (int i = 0; i < 11; ++i) s += row[i];
        k1[t] = row[t] / s;                  // == normalized 1D gaussian
    }
}

// ---------------- hierarchical 2x2 pools: s0 -> s1,s2,s3,s4 (pred and targ) ----------------
__global__ __launch_bounds__(256) void k_poolall(
        const float* __restrict__ p0, const float* __restrict__ t0,
        float* __restrict__ p1, float* __restrict__ t1,
        float* __restrict__ p2, float* __restrict__ t2,
        float* __restrict__ p3, float* __restrict__ t3,
        float* __restrict__ p4, float* __restrict__ t4) {
    __shared__ float l1[16][17];
    __shared__ float l2[8][9];
    __shared__ float l3[4][5];
    int t    = threadIdx.x;
    int tile = blockIdx.x;          // 256 tiles: 16x16 grid over the 256x256 s1 plane
    int pl   = blockIdx.y;
    int tY = tile >> 4, tX = tile & 15;

    const float* srcs[2] = {p0, t0};
    float* d1s[2] = {p1, t1};
    float* d2s[2] = {p2, t2};
    float* d3s[2] = {p3, t3};
    float* d4s[2] = {p4, t4};

    for (int a = 0; a < 2; ++a) {
        const float* src = srcs[a];
        int ty = t >> 4, tx = t & 15;
        int y1 = tY * 16 + ty, x1 = tX * 16 + tx;
        size_t b0 = (size_t)pl * 512 * 512 + (size_t)(2 * y1) * 512 + 2 * x1;
        float2 r0 = *(const float2*)(src + b0);
        float2 r1 = *(const float2*)(src + b0 + 512);
        float v1 = 0.25f * ((r0.x + r0.y) + (r1.x + r1.y));
        d1s[a][(size_t)pl * 256 * 256 + (size_t)y1 * 256 + x1] = v1;
        l1[ty][tx] = v1;
        __syncthreads();
        if (t < 64) {
            int y = t >> 3, x = t & 7;
            float v2 = 0.25f * (l1[2*y][2*x] + l1[2*y][2*x+1] + l1[2*y+1][2*x] + l1[2*y+1][2*x+1]);
            d2s[a][(size_t)pl * 128 * 128 + (size_t)(tY*8 + y) * 128 + (tX*8 + x)] = v2;
            l2[y][x] = v2;
        }
        __syncthreads();
        if (t < 16) {
            int y = t >> 2, x = t & 3;
            float v3 = 0.25f * (l2[2*y][2*x] + l2[2*y][2*x+1] + l2[2*y+1][2*x] + l2[2*y+1][2*x+1]);
            d3s[a][(size_t)pl * 64 * 64 + (size_t)(tY*4 + y) * 64 + (tX*4 + x)] = v3;
            l3[y][x] = v3;
        }
        __syncthreads();
        if (t < 4) {
            int y = t >> 1, x = t & 1;
            float v4 = 0.25f * (l3[2*y][2*x] + l3[2*y][2*x+1] + l3[2*y+1][2*x] + l3[2*y+1][2*x+1]);
            d4s[a][(size_t)pl * 32 * 32 + (size_t)(tY*2 + y) * 32 + (tX*2 + x)] = v4;
        }
        __syncthreads();
    }
}

// ---------------- sliding-window SSIM core: FAST = interior wave (imm-offset loads) ----------------
template<bool FAST>
__device__ __forceinline__ void ssim_cols(
        const float* __restrict__ Pp, const float* __restrict__ Tp,
        int H, int yb, int x, const float* __restrict__ w,
        const float* __restrict__ wc, const int* __restrict__ coff,
        float& lsum, float& csum)
{
    float wn0[11], wn1[11], wn2[11], wn3[11], wn4[11];
    const float C1 = 1e-4f, C2 = 9e-4f;
    const int BH = 32;
    int yend = yb + BH;
    int rr = yb - 5;
    const float* pP = Pp + (ptrdiff_t)rr * H + (FAST ? (x - 5) : 0);
    const float* pT = Tp + (ptrdiff_t)rr * H + (FAST ? (x - 5) : 0);

    for (int ch = 0; ch < 4; ++ch) {           // 4*11 = 44 slots >= BH+10 = 42
#pragma unroll
        for (int ph = 0; ph < 11; ++ph) {
            bool live = rr < yend + 5;
            float ap = 0.f, at = 0.f, app = 0.f, att = 0.f, apt = 0.f;
            if (live && rr >= 0 && rr < H) {   // uniform
#pragma unroll
                for (int j = 0; j < 11; ++j) {
                    float p, t, wj;
                    if (FAST) { p = pP[j];       t = pT[j];       wj = w[j]; }
                    else      { p = pP[coff[j]]; t = pT[coff[j]]; wj = wc[j]; }
                    float wp = wj * p, wt = wj * t;
                    ap  += wp;     at  += wt;
                    app += wp * p; att += wt * t; apt += wp * t;
                }
            }
            wn0[ph] = ap; wn1[ph] = at; wn2[ph] = app; wn3[ph] = att; wn4[ph] = apt;
            if (live && rr >= yb + 5) {        // uniform: emit output row rr-5
                float mu1 = 0.f, mu2 = 0.f, epp = 0.f, ett = 0.f, ept = 0.f;
#pragma unroll
                for (int i = 0; i < 11; ++i) {
                    const int sl = (ph + 1 + i) % 11;   // compile-time
                    mu1 += w[i] * wn0[sl];
                    mu2 += w[i] * wn1[sl];
                    epp += w[i] * wn2[sl];
                    ett += w[i] * wn3[sl];
                    ept += w[i] * wn4[sl];
                }
                float m11 = mu1 * mu1, m22 = mu2 * mu2, m12 = mu1 * mu2;
                float s1  = fmaxf(epp - m11, 0.f);
                float s2  = fmaxf(ett - m22, 0.f);
                float s12 = ept - m12;
                lsum += (2.f * m12 + C1) * __builtin_amdgcn_rcpf(m11 + m22 + C1);
                csum += (2.f * s12 + C2) * __builtin_amdgcn_rcpf(s1 + s2 + C2);
            }
            rr++; pP += H; pT += H;
        }
    }
}

// ---------------- fused all-scale SSIM, BH=32 rows per block ----------------
// Blocks: [0,1536) s0(512)  [1536,1920) s1(256)  [1920,2016) s2(128)
//         [2016,2040) s3(64)  [2040,2046) s4(32)
__global__ __launch_bounds__(256, 4) void k_ssim_all(
        const float* __restrict__ pred, const float* __restrict__ targ,
        const float* __restrict__ p1, const float* __restrict__ t1,
        const float* __restrict__ p2, const float* __restrict__ t2,
        const float* __restrict__ p3, const float* __restrict__ t3,
        const float* __restrict__ p4, const float* __restrict__ t4,
        const float* __restrict__ k1g, double* __restrict__ accum) {
    int b   = blockIdx.x;
    int tid = threadIdx.x;
    const float *P, *T;
    int H, sh, base, scale;
    if (b < 1536)      { scale = 0; H = 512; sh = 9; base = 0;    P = pred; T = targ; }
    else if (b < 1920) { scale = 1; H = 256; sh = 8; base = 1536; P = p1;   T = t1;   }
    else if (b < 2016) { scale = 2; H = 128; sh = 7; base = 1920; P = p2;   T = t2;   }
    else if (b < 2040) { scale = 3; H = 64;  sh = 6; base = 2016; P = p3;   T = t3;   }
    else               { scale = 4; H = 32;  sh = 5; base = 2040; P = p4;   T = t4;   }
    int lb      = b - base;
    int blocksX = (NP << sh) >> 8;          // 48*H / 256
    int bxi = lb % blocksX;
    int by  = lb / blocksX;
    int g   = (bxi << 8) + tid;
    int pl  = g >> sh;
    int x   = g & (H - 1);
    int yb  = by * 32;

    const float* Pp = P + (size_t)pl * H * H;
    const float* Tp = T + (size_t)pl * H * H;

    float w[11];
#pragma unroll
    for (int j = 0; j < 11; ++j) w[j] = k1g[j];

    float lsum = 0.f, csum = 0.f;
    int x0 = x & ~63;                        // wave-uniform for H>=64; 0 for H=32
    bool fast = (x0 != 0) && (x0 != H - 64); // all taps in-bounds for the whole wave
    if (fast) {
        ssim_cols<true>(Pp, Tp, H, yb, x, w, nullptr, nullptr, lsum, csum);
    } else {
        float wc[11];
        int coff[11];
#pragma unroll
        for (int j = 0; j < 11; ++j) {
            int gx = x - 5 + j;
            coff[j] = gx < 0 ? 0 : (gx > H - 1 ? H - 1 : gx);
            wc[j]   = (gx >= 0 && gx < H) ? w[j] : 0.f;
        }
        ssim_cols<false>(Pp, Tp, H, yb, x, w, wc, coff, lsum, csum);
    }

    // wave shuffle reduce then cross-wave via LDS
#pragma unroll
    for (int o = 32; o > 0; o >>= 1) {
        lsum += __shfl_down(lsum, o, 64);
        csum += __shfl_down(csum, o, 64);
    }
    __shared__ float red[8];
    int wv = tid >> 6;
    if ((tid & 63) == 0) { red[2 * wv] = lsum; red[2 * wv + 1] = csum; }
    __syncthreads();
    if (tid == 0) {
        int slot = (scale * 8 + (b & 7)) * 2;
        atomicAdd(&accum[slot],     (double)(red[0] + red[2] + red[4] + red[6]));
        atomicAdd(&accum[slot + 1], (double)(red[1] + red[3] + red[5] + red[7]));
    }
}

// ---------------- finalize: weighted power product ----------------
__global__ void k_final(const double* __restrict__ accum, float* __restrict__ out) {
    if (threadIdx.x != 0 || blockIdx.x != 0) return;
    const double wts[5] = {0.0448, 0.2856, 0.3001, 0.2363, 0.1333};
    double ms = 1.0;
    int Hs = 512;
    for (int s = 0; s < 5; ++s) {
        double lt = 0.0, ct = 0.0;
        for (int k = 0; k < 8; ++k) {
            lt += accum[(s * 8 + k) * 2];
            ct += accum[(s * 8 + k) * 2 + 1];
        }
        double N  = 48.0 * (double)Hs * (double)Hs;
        double l  = lt / N;
        double cs = ct / N;
        if (cs < 1e-8) cs = 1e-8;
        if (s == 4) {
            if (l < 1e-8) l = 1e-8;
            ms *= pow(l, wts[s]) * pow(cs, wts[s]);
        } else {
            ms *= pow(cs, wts[s]);
        }
        Hs >>= 1;
    }
    out[0] = (float)ms;
}

extern "C" void kernel_launch(void* const* d_in, const int* in_sizes, int n_in,
                              void* d_out, int out_size, void* d_ws, size_t ws_size,
                              hipStream_t stream) {
    const float* pred = (const float*)d_in[0];
    const float* targ = (const float*)d_in[1];
    const float* kern = (const float*)d_in[2];
    float* out = (float*)d_out;

    char* ws = (char*)d_ws;
    double* accum = (double*)ws;             // 80 doubles (5 scales * 8 slots * 2)
    float*  k1    = (float*)(ws + 768);      // 11 floats
    size_t off = 1024;
    float* p1 = (float*)(ws + off); off += (size_t)NP * 256 * 256 * 4;
    float* t1 = (float*)(ws + off); off += (size_t)NP * 256 * 256 * 4;
    float* p2 = (float*)(ws + off); off += (size_t)NP * 128 * 128 * 4;
    float* t2 = (float*)(ws + off); off += (size_t)NP * 128 * 128 * 4;
    float* p3 = (float*)(ws + off); off += (size_t)NP * 64 * 64 * 4;
    float* t3 = (float*)(ws + off); off += (size_t)NP * 64 * 64 * 4;
    float* p4 = (float*)(ws + off); off += (size_t)NP * 32 * 32 * 4;
    float* t4 = (float*)(ws + off); off += (size_t)NP * 32 * 32 * 4;

    hipMemsetAsync(accum, 0, 640, stream);
    k_extract<<<1, 64, 0, stream>>>(kern, k1);
    k_poolall<<<dim3(256, NP), 256, 0, stream>>>(pred, targ, p1, t1, p2, t2, p3, t3, p4, t4);
    k_ssim_all<<<2046, 256, 0, stream>>>(pred, targ, p1, t1, p2, t2, p3, t3, p4, t4, k1, accum);
    k_final<<<1, 1, 0, stream>>>(accum, out);
}

// Round 5
// 279.876 us; speedup vs baseline: 1.9841x; 1.9841x over previous
//
#include <hip/hip_runtime.h>
#include <math.h>

#define NP 48   // 16 batch * 3 channels

__device__ __forceinline__ float uniform_f(float v) {
    // correct wave-uniform pin to SGPR: bitcast, readfirstlane on the int, bitcast back
    int i = __builtin_amdgcn_readfirstlane(__builtin_bit_cast(int, v));
    return __builtin_bit_cast(float, i);
}

// ---------------- extract normalized 1D kernel from provided 2D kernel ----------------
__global__ __launch_bounds__(64) void k_extract(const float* __restrict__ kern,
                                                float* __restrict__ k1) {
    __shared__ float row[11];
    int t = threadIdx.x;
    if (t < 11) row[t] = kern[5 * 11 + t];   // center row of the 11x11 kernel
    __syncthreads();
    if (t < 11) {
        float s = 0.f;
#pragma unroll
        for (int i = 0; i < 11; ++i) s += row[i];
        k1[t] = row[t] / s;                  // == normalized 1D gaussian
    }
}

// ---------------- hierarchical 2x2 pools: s0 -> s1,s2,s3,s4 (pred and targ) ----------------
__global__ __launch_bounds__(256) void k_poolall(
        const float* __restrict__ p0, const float* __restrict__ t0,
        float* __restrict__ p1, float* __restrict__ t1,
        float* __restrict__ p2, float* __restrict__ t2,
        float* __restrict__ p3, float* __restrict__ t3,
        float* __restrict__ p4, float* __restrict__ t4) {
    __shared__ float l1[16][17];
    __shared__ float l2[8][9];
    __shared__ float l3[4][5];
    int t    = threadIdx.x;
    int tile = blockIdx.x;          // 256 tiles: 16x16 grid over the 256x256 s1 plane
    int pl   = blockIdx.y;
    int tY = tile >> 4, tX = tile & 15;

    const float* srcs[2] = {p0, t0};
    float* d1s[2] = {p1, t1};
    float* d2s[2] = {p2, t2};
    float* d3s[2] = {p3, t3};
    float* d4s[2] = {p4, t4};

    for (int a = 0; a < 2; ++a) {
        const float* src = srcs[a];
        int ty = t >> 4, tx = t & 15;
        int y1 = tY * 16 + ty, x1 = tX * 16 + tx;
        size_t b0 = (size_t)pl * 512 * 512 + (size_t)(2 * y1) * 512 + 2 * x1;
        float2 r0 = *(const float2*)(src + b0);
        float2 r1 = *(const float2*)(src + b0 + 512);
        float v1 = 0.25f * ((r0.x + r0.y) + (r1.x + r1.y));
        d1s[a][(size_t)pl * 256 * 256 + (size_t)y1 * 256 + x1] = v1;
        l1[ty][tx] = v1;
        __syncthreads();
        if (t < 64) {
            int y = t >> 3, x = t & 7;
            float v2 = 0.25f * (l1[2*y][2*x] + l1[2*y][2*x+1] + l1[2*y+1][2*x] + l1[2*y+1][2*x+1]);
            d2s[a][(size_t)pl * 128 * 128 + (size_t)(tY*8 + y) * 128 + (tX*8 + x)] = v2;
            l2[y][x] = v2;
        }
        __syncthreads();
        if (t < 16) {
            int y = t >> 2, x = t & 3;
            float v3 = 0.25f * (l2[2*y][2*x] + l2[2*y][2*x+1] + l2[2*y+1][2*x] + l2[2*y+1][2*x+1]);
            d3s[a][(size_t)pl * 64 * 64 + (size_t)(tY*4 + y) * 64 + (tX*4 + x)] = v3;
            l3[y][x] = v3;
        }
        __syncthreads();
        if (t < 4) {
            int y = t >> 1, x = t & 1;
            float v4 = 0.25f * (l3[2*y][2*x] + l3[2*y][2*x+1] + l3[2*y+1][2*x] + l3[2*y+1][2*x+1]);
            d4s[a][(size_t)pl * 32 * 32 + (size_t)(tY*2 + y) * 32 + (tX*2 + x)] = v4;
        }
        __syncthreads();
    }
}

// ---------------- sliding-window SSIM core: FAST = interior wave (imm-offset loads) ----------------
template<bool FAST>
__device__ __forceinline__ void ssim_cols(
        const float* __restrict__ Pp, const float* __restrict__ Tp,
        int H, int yb, int x, const float* __restrict__ w,
        const float* __restrict__ wc, const int* __restrict__ coff,
        float& lsum, float& csum)
{
    float wn0[11], wn1[11], wn2[11], wn3[11], wn4[11];
    const float C1 = 1e-4f, C2 = 9e-4f;
    const int BH = 32;
    int yend = yb + BH;
    int rr = yb - 5;
    const float* pP = Pp + (ptrdiff_t)rr * H + (FAST ? (x - 5) : 0);
    const float* pT = Tp + (ptrdiff_t)rr * H + (FAST ? (x - 5) : 0);

    for (int ch = 0; ch < 4; ++ch) {           // 4*11 = 44 slots >= BH+10 = 42
#pragma unroll
        for (int ph = 0; ph < 11; ++ph) {
            bool live = rr < yend + 5;
            float ap = 0.f, at = 0.f, app = 0.f, att = 0.f, apt = 0.f;
            if (live && rr >= 0 && rr < H) {   // uniform
#pragma unroll
                for (int j = 0; j < 11; ++j) {
                    float p, t, wj;
                    if (FAST) { p = pP[j];       t = pT[j];       wj = w[j]; }
                    else      { p = pP[coff[j]]; t = pT[coff[j]]; wj = wc[j]; }
                    float wp = wj * p, wt = wj * t;
                    ap  += wp;     at  += wt;
                    app += wp * p; att += wt * t; apt += wp * t;
                }
            }
            wn0[ph] = ap; wn1[ph] = at; wn2[ph] = app; wn3[ph] = att; wn4[ph] = apt;
            if (live && rr >= yb + 5) {        // uniform: emit output row rr-5
                float mu1 = 0.f, mu2 = 0.f, epp = 0.f, ett = 0.f, ept = 0.f;
#pragma unroll
                for (int i = 0; i < 11; ++i) {
                    const int sl = (ph + 1 + i) % 11;   // compile-time
                    mu1 += w[i] * wn0[sl];
                    mu2 += w[i] * wn1[sl];
                    epp += w[i] * wn2[sl];
                    ett += w[i] * wn3[sl];
                    ept += w[i] * wn4[sl];
                }
                float m11 = mu1 * mu1, m22 = mu2 * mu2, m12 = mu1 * mu2;
                float s1  = fmaxf(epp - m11, 0.f);
                float s2  = fmaxf(ett - m22, 0.f);
                float s12 = ept - m12;
                lsum += (2.f * m12 + C1) * __builtin_amdgcn_rcpf(m11 + m22 + C1);
                csum += (2.f * s12 + C2) * __builtin_amdgcn_rcpf(s1 + s2 + C2);
            }
            rr++; pP += H; pT += H;
        }
    }
}

// ---------------- fused all-scale SSIM, BH=32 rows per block ----------------
// Blocks: [0,1536) s0(512)  [1536,1920) s1(256)  [1920,2016) s2(128)
//         [2016,2040) s3(64)  [2040,2046) s4(32)
__global__ __launch_bounds__(256) void k_ssim_all(
        const float* __restrict__ pred, const float* __restrict__ targ,
        const float* __restrict__ p1, const float* __restrict__ t1,
        const float* __restrict__ p2, const float* __restrict__ t2,
        const float* __restrict__ p3, const float* __restrict__ t3,
        const float* __restrict__ p4, const float* __restrict__ t4,
        const float* __restrict__ k1g, double* __restrict__ accum) {
    int b   = blockIdx.x;
    int tid = threadIdx.x;
    const float *P, *T;
    int H, sh, base, scale;
    if (b < 1536)      { scale = 0; H = 512; sh = 9; base = 0;    P = pred; T = targ; }
    else if (b < 1920) { scale = 1; H = 256; sh = 8; base = 1536; P = p1;   T = t1;   }
    else if (b < 2016) { scale = 2; H = 128; sh = 7; base = 1920; P = p2;   T = t2;   }
    else if (b < 2040) { scale = 3; H = 64;  sh = 6; base = 2016; P = p3;   T = t3;   }
    else               { scale = 4; H = 32;  sh = 5; base = 2040; P = p4;   T = t4;   }
    int lb      = b - base;
    int blocksX = (NP << sh) >> 8;          // 48*H / 256
    int bxi = lb % blocksX;
    int by  = lb / blocksX;
    int g   = (bxi << 8) + tid;
    int pl  = g >> sh;
    int x   = g & (H - 1);
    int yb  = by * 32;

    const float* Pp = P + (size_t)pl * H * H;
    const float* Tp = T + (size_t)pl * H * H;

    // wave-uniform weights -> SGPRs (bitcast readfirstlane; float overload TRUNCATES!)
    float w[11];
#pragma unroll
    for (int j = 0; j < 11; ++j) w[j] = uniform_f(k1g[j]);

    float lsum = 0.f, csum = 0.f;
    int x0 = x & ~63;                        // wave-uniform for H>=64; 0 for H=32
    bool fast = (x0 != 0) && (x0 != H - 64); // all taps in-bounds for the whole wave
    if (fast) {
        ssim_cols<true>(Pp, Tp, H, yb, x, w, nullptr, nullptr, lsum, csum);
    } else {
        float wc[11];
        int coff[11];
#pragma unroll
        for (int j = 0; j < 11; ++j) {
            int gx = x - 5 + j;
            coff[j] = gx < 0 ? 0 : (gx > H - 1 ? H - 1 : gx);
            wc[j]   = (gx >= 0 && gx < H) ? w[j] : 0.f;
        }
        ssim_cols<false>(Pp, Tp, H, yb, x, w, wc, coff, lsum, csum);
    }

    // wave shuffle reduce then cross-wave via LDS
#pragma unroll
    for (int o = 32; o > 0; o >>= 1) {
        lsum += __shfl_down(lsum, o, 64);
        csum += __shfl_down(csum, o, 64);
    }
    __shared__ float red[8];
    int wv = tid >> 6;
    if ((tid & 63) == 0) { red[2 * wv] = lsum; red[2 * wv + 1] = csum; }
    __syncthreads();
    if (tid == 0) {
        int slot = (scale * 8 + (b & 7)) * 2;
        atomicAdd(&accum[slot],     (double)(red[0] + red[2] + red[4] + red[6]));
        atomicAdd(&accum[slot + 1], (double)(red[1] + red[3] + red[5] + red[7]));
    }
}

// ---------------- finalize: weighted power product ----------------
__global__ void k_final(const double* __restrict__ accum, float* __restrict__ out) {
    if (threadIdx.x != 0 || blockIdx.x != 0) return;
    const double wts[5] = {0.0448, 0.2856, 0.3001, 0.2363, 0.1333};
    double ms = 1.0;
    int Hs = 512;
    for (int s = 0; s < 5; ++s) {
        double lt = 0.0, ct = 0.0;
        for (int k = 0; k < 8; ++k) {
            lt += accum[(s * 8 + k) * 2];
            ct += accum[(s * 8 + k) * 2 + 1];
        }
        double N  = 48.0 * (double)Hs * (double)Hs;
        double l  = lt / N;
        double cs = ct / N;
        if (cs < 1e-8) cs = 1e-8;
        if (s == 4) {
            if (l < 1e-8) l = 1e-8;
            ms *= pow(l, wts[s]) * pow(cs, wts[s]);
        } else {
            ms *= pow(cs, wts[s]);
        }
        Hs >>= 1;
    }
    out[0] = (float)ms;
}

extern "C" void kernel_launch(void* const* d_in, const int* in_sizes, int n_in,
                              void* d_out, int out_size, void* d_ws, size_t ws_size,
                              hipStream_t stream) {
    const float* pred = (const float*)d_in[0];
    const float* targ = (const float*)d_in[1];
    const float* kern = (const float*)d_in[2];
    float* out = (float*)d_out;

    char* ws = (char*)d_ws;
    double* accum = (double*)ws;             // 80 doubles (5 scales * 8 slots * 2)
    float*  k1    = (float*)(ws + 768);      // 11 floats
    size_t off = 1024;
    float* p1 = (float*)(ws + off); off += (size_t)NP * 256 * 256 * 4;
    float* t1 = (float*)(ws + off); off += (size_t)NP * 256 * 256 * 4;
    float* p2 = (float*)(ws + off); off += (size_t)NP * 128 * 128 * 4;
    float* t2 = (float*)(ws + off); off += (size_t)NP * 128 * 128 * 4;
    float* p3 = (float*)(ws + off); off += (size_t)NP * 64 * 64 * 4;
    float* t3 = (float*)(ws + off); off += (size_t)NP * 64 * 64 * 4;
    float* p4 = (float*)(ws + off); off += (size_t)NP * 32 * 32 * 4;
    float* t4 = (float*)(ws + off); off += (size_t)NP * 32 * 32 * 4;

    hipMemsetAsync(accum, 0, 640, stream);
    k_extract<<<1, 64, 0, stream>>>(kern, k1);
    k_poolall<<<dim3(256, NP), 256, 0, stream>>>(pred, targ, p1, t1, p2, t2, p3, t3, p4, t4);
    k_ssim_all<<<2046, 256, 0, stream>>>(pred, targ, p1, t1, p2, t2, p3, t3, p4, t4, k1, accum);
    k_final<<<1, 1, 0, stream>>>(accum, out);
}

// Round 6
// 237.853 us; speedup vs baseline: 2.3347x; 1.1767x over previous
//
#include <hip/hip_runtime.h>
#include <math.h>

#define NP 48   // 16 batch * 3 channels

typedef float v2f __attribute__((ext_vector_type(2)));

// ---------------- 2x2 pools: s0 -> s1,s2,s3,s4; blockIdx.z selects pred/targ ----------------
__global__ __launch_bounds__(256) void k_poolall(
        const float* __restrict__ p0, const float* __restrict__ t0,
        float* __restrict__ p1, float* __restrict__ t1,
        float* __restrict__ p2, float* __restrict__ t2,
        float* __restrict__ p3, float* __restrict__ t3,
        float* __restrict__ p4, float* __restrict__ t4) {
    __shared__ float l1[16][17];
    __shared__ float l2[8][9];
    __shared__ float l3[4][5];
    int t    = threadIdx.x;
    int tile = blockIdx.x;          // 256 tiles: 16x16 grid over the 256x256 s1 plane
    int pl   = blockIdx.y;
    int z    = blockIdx.z;          // 0 = pred, 1 = targ
    int tY = tile >> 4, tX = tile & 15;

    const float* src = z ? t0 : p0;
    float* d1 = z ? t1 : p1;
    float* d2 = z ? t2 : p2;
    float* d3 = z ? t3 : p3;
    float* d4 = z ? t4 : p4;

    int ty = t >> 4, tx = t & 15;
    int y1 = tY * 16 + ty, x1 = tX * 16 + tx;
    size_t b0 = (size_t)pl * 512 * 512 + (size_t)(2 * y1) * 512 + 2 * x1;
    float2 r0 = *(const float2*)(src + b0);
    float2 r1 = *(const float2*)(src + b0 + 512);
    float v1 = 0.25f * ((r0.x + r0.y) + (r1.x + r1.y));
    d1[(size_t)pl * 256 * 256 + (size_t)y1 * 256 + x1] = v1;
    l1[ty][tx] = v1;
    __syncthreads();
    if (t < 64) {
        int y = t >> 3, x = t & 7;
        float v2 = 0.25f * (l1[2*y][2*x] + l1[2*y][2*x+1] + l1[2*y+1][2*x] + l1[2*y+1][2*x+1]);
        d2[(size_t)pl * 128 * 128 + (size_t)(tY*8 + y) * 128 + (tX*8 + x)] = v2;
        l2[y][x] = v2;
    }
    __syncthreads();
    if (t < 16) {
        int y = t >> 2, x = t & 3;
        float v3 = 0.25f * (l2[2*y][2*x] + l2[2*y][2*x+1] + l2[2*y+1][2*x] + l2[2*y+1][2*x+1]);
        d3[(size_t)pl * 64 * 64 + (size_t)(tY*4 + y) * 64 + (tX*4 + x)] = v3;
        l3[y][x] = v3;
    }
    __syncthreads();
    if (t < 4) {
        int y = t >> 1, x = t & 1;
        float v4 = 0.25f * (l3[2*y][2*x] + l3[2*y][2*x+1] + l3[2*y+1][2*x] + l3[2*y+1][2*x+1]);
        d4[(size_t)pl * 32 * 32 + (size_t)(tY*2 + y) * 32 + (tX*2 + x)] = v4;
    }
}

// ---------------- fused all-scale SSIM, BH=32 rows per block, pk-packed p/t ----------------
// Blocks: [0,1536) s0(512)  [1536,1920) s1(256)  [1920,2016) s2(128)
//         [2016,2040) s3(64)  [2040,2046) s4(32)
__global__ __launch_bounds__(256) void k_ssim_all(
        const float* __restrict__ pred, const float* __restrict__ targ,
        const float* __restrict__ p1, const float* __restrict__ t1,
        const float* __restrict__ p2, const float* __restrict__ t2,
        const float* __restrict__ p3, const float* __restrict__ t3,
        const float* __restrict__ p4, const float* __restrict__ t4,
        const float* __restrict__ k2d, double* __restrict__ accum) {
    int b   = blockIdx.x;
    int tid = threadIdx.x;
    const float *P, *T;
    int H, sh, base, scale;
    if (b < 1536)      { scale = 0; H = 512; sh = 9; base = 0;    P = pred; T = targ; }
    else if (b < 1920) { scale = 1; H = 256; sh = 8; base = 1536; P = p1;   T = t1;   }
    else if (b < 2016) { scale = 2; H = 128; sh = 7; base = 1920; P = p2;   T = t2;   }
    else if (b < 2040) { scale = 3; H = 64;  sh = 6; base = 2016; P = p3;   T = t3;   }
    else               { scale = 4; H = 32;  sh = 5; base = 2040; P = p4;   T = t4;   }
    int lb      = b - base;
    int blocksX = (NP << sh) >> 8;          // 48*H / 256
    int bxi = lb % blocksX;
    int by  = lb / blocksX;
    int g   = (bxi << 8) + tid;
    int pl  = g >> sh;
    int x   = g & (H - 1);
    int yb  = by * 32;
    int yend = yb + 32;

    // derive normalized 1D gaussian from center row of 2D kernel (uniform -> s_loads/SGPRs)
    float w[11];
    {
        float s = 0.f;
#pragma unroll
        for (int i = 0; i < 11; ++i) s += k2d[55 + i];
        float inv = 1.0f / s;
#pragma unroll
        for (int i = 0; i < 11; ++i) w[i] = k2d[55 + i] * inv;
    }

    const float* Pp = P + (size_t)pl * H * H;
    const float* Tp = T + (size_t)pl * H * H;

    // per-lane clamped window base + edge-zeroed weights (one unified load path)
    int bcl = x - 5;
    bcl = bcl < 0 ? 0 : bcl;
    bcl = bcl > H - 11 ? H - 11 : bcl;
    int d = bcl - (x - 5);                  // in [-5, 5]; 0 for interior lanes
    v2f wc2[11];
#pragma unroll
    for (int j = 0; j < 11; ++j) {
        int idx = j + d;
        float val = 0.f;
#pragma unroll
        for (int i = 0; i < 11; ++i) val = (idx == i) ? w[i] : val;
        wc2[j] = (v2f){val, val};
    }
    v2f w2v[11];
#pragma unroll
    for (int i = 0; i < 11; ++i) w2v[i] = (v2f){w[i], w[i]};

    v2f wmu[11], we[11];                    // h-blur windows: {mu_p, mu_t}, {e_pp, e_tt}
    float wpt[11];                          // e_pt
    const float C1 = 1e-4f, C2 = 9e-4f;
    float lsum = 0.f, csum = 0.f;

    int rr = yb - 5;
    const float* pP = Pp + (ptrdiff_t)rr * H + bcl;
    const float* pT = Tp + (ptrdiff_t)rr * H + bcl;

    for (int ch = 0; ch < 4; ++ch) {        // 4*11 = 44 slots >= 42 steps
#pragma unroll
        for (int ph = 0; ph < 11; ++ph) {
            bool live = rr < yend + 5;
            v2f a_mu = (v2f){0.f, 0.f};
            v2f a_e  = (v2f){0.f, 0.f};
            float a_pt = 0.f;
            if (live && rr >= 0 && rr < H) {   // uniform row guard
#pragma unroll
                for (int j = 0; j < 11; ++j) {
                    v2f pt2 = (v2f){pP[j], pT[j]};
                    v2f wp2 = wc2[j] * pt2;
                    a_mu += wp2;
                    a_e  += wp2 * pt2;
                    a_pt += wp2.x * pt2.y;
                }
            }
            wmu[ph] = a_mu; we[ph] = a_e; wpt[ph] = a_pt;
            if (live && rr >= yb + 5) {        // emit output row rr-5
                v2f mu2 = (v2f){0.f, 0.f};
                v2f e2  = (v2f){0.f, 0.f};
                float ept = 0.f;
#pragma unroll
                for (int i = 0; i < 11; ++i) {
                    const int sl = (ph + 1 + i) % 11;   // compile-time
                    mu2 += w2v[i] * wmu[sl];
                    e2  += w2v[i] * we[sl];
                    ept += w[i] * wpt[sl];
                }
                float m11 = mu2.x * mu2.x, m22 = mu2.y * mu2.y, m12 = mu2.x * mu2.y;
                float s1  = fmaxf(e2.x - m11, 0.f);
                float s2  = fmaxf(e2.y - m22, 0.f);
                float s12 = ept - m12;
                lsum += (2.f * m12 + C1) * __builtin_amdgcn_rcpf(m11 + m22 + C1);
                csum += (2.f * s12 + C2) * __builtin_amdgcn_rcpf(s1 + s2 + C2);
            }
            rr++; pP += H; pT += H;
        }
    }

    // wave shuffle reduce then cross-wave via LDS
#pragma unroll
    for (int o = 32; o > 0; o >>= 1) {
        lsum += __shfl_down(lsum, o, 64);
        csum += __shfl_down(csum, o, 64);
    }
    __shared__ float red[8];
    int wv = tid >> 6;
    if ((tid & 63) == 0) { red[2 * wv] = lsum; red[2 * wv + 1] = csum; }
    __syncthreads();
    if (tid == 0) {
        int slot = (scale * 8 + (b & 7)) * 2;
        atomicAdd(&accum[slot],     (double)(red[0] + red[2] + red[4] + red[6]));
        atomicAdd(&accum[slot + 1], (double)(red[1] + red[3] + red[5] + red[7]));
    }
}

// ---------------- finalize: weighted power product ----------------
__global__ void k_final(const double* __restrict__ accum, float* __restrict__ out) {
    if (threadIdx.x != 0 || blockIdx.x != 0) return;
    const double wts[5] = {0.0448, 0.2856, 0.3001, 0.2363, 0.1333};
    double ms = 1.0;
    int Hs = 512;
    for (int s = 0; s < 5; ++s) {
        double lt = 0.0, ct = 0.0;
        for (int k = 0; k < 8; ++k) {
            lt += accum[(s * 8 + k) * 2];
            ct += accum[(s * 8 + k) * 2 + 1];
        }
        double N  = 48.0 * (double)Hs * (double)Hs;
        double l  = lt / N;
        double cs = ct / N;
        if (cs < 1e-8) cs = 1e-8;
        if (s == 4) {
            if (l < 1e-8) l = 1e-8;
            ms *= pow(l, wts[s]) * pow(cs, wts[s]);
        } else {
            ms *= pow(cs, wts[s]);
        }
        Hs >>= 1;
    }
    out[0] = (float)ms;
}

extern "C" void kernel_launch(void* const* d_in, const int* in_sizes, int n_in,
                              void* d_out, int out_size, void* d_ws, size_t ws_size,
                              hipStream_t stream) {
    const float* pred = (const float*)d_in[0];
    const float* targ = (const float*)d_in[1];
    const float* kern = (const float*)d_in[2];
    float* out = (float*)d_out;

    char* ws = (char*)d_ws;
    double* accum = (double*)ws;             // 80 doubles (5 scales * 8 slots * 2)
    size_t off = 1024;
    float* p1 = (float*)(ws + off); off += (size_t)NP * 256 * 256 * 4;
    float* t1 = (float*)(ws + off); off += (size_t)NP * 256 * 256 * 4;
    float* p2 = (float*)(ws + off); off += (size_t)NP * 128 * 128 * 4;
    float* t2 = (float*)(ws + off); off += (size_t)NP * 128 * 128 * 4;
    float* p3 = (float*)(ws + off); off += (size_t)NP * 64 * 64 * 4;
    float* t3 = (float*)(ws + off); off += (size_t)NP * 64 * 64 * 4;
    float* p4 = (float*)(ws + off); off += (size_t)NP * 32 * 32 * 4;
    float* t4 = (float*)(ws + off); off += (size_t)NP * 32 * 32 * 4;

    hipMemsetAsync(accum, 0, 640, stream);
    k_poolall<<<dim3(256, NP, 2), 256, 0, stream>>>(pred, targ, p1, t1, p2, t2, p3, t3, p4, t4);
    k_ssim_all<<<2046, 256, 0, stream>>>(pred, targ, p1, t1, p2, t2, p3, t3, p4, t4, kern, accum);
    k_final<<<1, 1, 0, stream>>>(accum, out);
}

// Round 7
// 237.168 us; speedup vs baseline: 2.3414x; 1.0029x over previous
//
#include <hip/hip_runtime.h>
#include <math.h>

#define NP 48   // 16 batch * 3 channels

typedef float v2f __attribute__((ext_vector_type(2)));

// ---------------- shared SSIM core (round-6 tuned version, unchanged math) ----------------
__device__ __forceinline__ void ssim_scale(
        const float* __restrict__ P, const float* __restrict__ T,
        int H, int sh, int lb, int scale, int slotsel, int tid,
        const float* __restrict__ k2d, double* __restrict__ accum)
{
    // derive normalized 1D gaussian from center row of 2D kernel (uniform -> SGPRs)
    float w[11];
    {
        float s = 0.f;
#pragma unroll
        for (int i = 0; i < 11; ++i) s += k2d[55 + i];
        float inv = 1.0f / s;
#pragma unroll
        for (int i = 0; i < 11; ++i) w[i] = k2d[55 + i] * inv;
    }

    int blocksX = (NP << sh) >> 8;          // 48*H / 256
    int bxi = lb % blocksX;
    int by  = lb / blocksX;
    int g   = (bxi << 8) + tid;
    int pl  = g >> sh;
    int x   = g & (H - 1);
    int yb  = by * 32;
    int yend = yb + 32;

    const float* Pp = P + (size_t)pl * H * H;
    const float* Tp = T + (size_t)pl * H * H;

    // per-lane clamped window base + edge-zeroed weights (one unified load path)
    int bcl = x - 5;
    bcl = bcl < 0 ? 0 : bcl;
    bcl = bcl > H - 11 ? H - 11 : bcl;
    int d = bcl - (x - 5);                  // in [-5, 5]; 0 for interior lanes
    v2f wc2[11];
#pragma unroll
    for (int j = 0; j < 11; ++j) {
        int idx = j + d;
        float val = 0.f;
#pragma unroll
        for (int i = 0; i < 11; ++i) val = (idx == i) ? w[i] : val;
        wc2[j] = (v2f){val, val};
    }
    v2f w2v[11];
#pragma unroll
    for (int i = 0; i < 11; ++i) w2v[i] = (v2f){w[i], w[i]};

    v2f wmu[11], we[11];                    // h-blur windows: {mu_p, mu_t}, {e_pp, e_tt}
    float wpt[11];                          // e_pt
    const float C1 = 1e-4f, C2 = 9e-4f;
    float lsum = 0.f, csum = 0.f;

    int rr = yb - 5;
    const float* pP = Pp + (ptrdiff_t)rr * H + bcl;
    const float* pT = Tp + (ptrdiff_t)rr * H + bcl;

    for (int ch = 0; ch < 4; ++ch) {        // 4*11 = 44 slots >= 42 steps
#pragma unroll
        for (int ph = 0; ph < 11; ++ph) {
            bool live = rr < yend + 5;
            v2f a_mu = (v2f){0.f, 0.f};
            v2f a_e  = (v2f){0.f, 0.f};
            float a_pt = 0.f;
            if (live && rr >= 0 && rr < H) {   // uniform row guard
#pragma unroll
                for (int j = 0; j < 11; ++j) {
                    v2f pt2 = (v2f){pP[j], pT[j]};
                    v2f wp2 = wc2[j] * pt2;
                    a_mu += wp2;
                    a_e  += wp2 * pt2;
                    a_pt += wp2.x * pt2.y;
                }
            }
            wmu[ph] = a_mu; we[ph] = a_e; wpt[ph] = a_pt;
            if (live && rr >= yb + 5) {        // emit output row rr-5
                v2f mu2 = (v2f){0.f, 0.f};
                v2f e2  = (v2f){0.f, 0.f};
                float ept = 0.f;
#pragma unroll
                for (int i = 0; i < 11; ++i) {
                    const int sl = (ph + 1 + i) % 11;   // compile-time
                    mu2 += w2v[i] * wmu[sl];
                    e2  += w2v[i] * we[sl];
                    ept += w[i] * wpt[sl];
                }
                float m11 = mu2.x * mu2.x, m22 = mu2.y * mu2.y, m12 = mu2.x * mu2.y;
                float s1  = fmaxf(e2.x - m11, 0.f);
                float s2  = fmaxf(e2.y - m22, 0.f);
                float s12 = ept - m12;
                lsum += (2.f * m12 + C1) * __builtin_amdgcn_rcpf(m11 + m22 + C1);
                csum += (2.f * s12 + C2) * __builtin_amdgcn_rcpf(s1 + s2 + C2);
            }
            rr++; pP += H; pT += H;
        }
    }

    // wave shuffle reduce then cross-wave via LDS
#pragma unroll
    for (int o = 32; o > 0; o >>= 1) {
        lsum += __shfl_down(lsum, o, 64);
        csum += __shfl_down(csum, o, 64);
    }
    __shared__ float red[8];
    int wv = tid >> 6;
    if ((tid & 63) == 0) { red[2 * wv] = lsum; red[2 * wv + 1] = csum; }
    __syncthreads();
    if (tid == 0) {
        int slot = (scale * 8 + slotsel) * 2;
        atomicAdd(&accum[slot],     (double)(red[0] + red[2] + red[4] + red[6]));
        atomicAdd(&accum[slot + 1], (double)(red[1] + red[3] + red[5] + red[7]));
    }
}

// ---------------- kernel A: pool blocks [0,1536) || ssim scale-0 blocks [1536,3072) ----------------
__global__ __launch_bounds__(256) void k_main(
        const float* __restrict__ pred, const float* __restrict__ targ,
        float* __restrict__ p1, float* __restrict__ t1,
        float* __restrict__ p2, float* __restrict__ t2,
        float* __restrict__ p3, float* __restrict__ t3,
        float* __restrict__ p4, float* __restrict__ t4,
        const float* __restrict__ k2d, double* __restrict__ accum) {
    int b   = blockIdx.x;
    int tid = threadIdx.x;
    if (b >= 1536) {
        ssim_scale(pred, targ, 512, 9, b - 1536, 0, b & 7, tid, k2d, accum);
        return;
    }
    // ---- pool path: 64x64 s1 tile; all scales from s0 (mean of means) ----
    int pi   = b >> 4;          // 0..95 plane-image
    int tile = b & 15;          // 4x4 tiles over the 256x256 s1 plane
    int pls  = pi < 48 ? pi : pi - 48;
    const float* src = (pi < 48 ? pred : targ) + (size_t)pls * 512 * 512;
    float* d1 = (pi < 48 ? p1 : t1) + (size_t)pls * 256 * 256;
    float* d2 = (pi < 48 ? p2 : t2) + (size_t)pls * 128 * 128;
    float* d3 = (pi < 48 ? p3 : t3) + (size_t)pls * 64 * 64;
    float* d4 = (pi < 48 ? p4 : t4) + (size_t)pls * 32 * 32;
    int tY = tile >> 2, tX = tile & 3;
    int ty = tid >> 4, tx = tid & 15;
    int gy0 = tY * 128 + ty * 8, gx0 = tX * 128 + tx * 8;

    float s1v[4][4];
#pragma unroll
    for (int i = 0; i < 4; ++i) {
        const float* r0 = src + (size_t)(gy0 + 2 * i) * 512 + gx0;
        const float* r1 = r0 + 512;
        float4 a0 = *(const float4*)r0, a1 = *(const float4*)(r0 + 4);
        float4 b0 = *(const float4*)r1, b1 = *(const float4*)(r1 + 4);
        s1v[i][0] = 0.25f * ((a0.x + a0.y) + (b0.x + b0.y));
        s1v[i][1] = 0.25f * ((a0.z + a0.w) + (b0.z + b0.w));
        s1v[i][2] = 0.25f * ((a1.x + a1.y) + (b1.x + b1.y));
        s1v[i][3] = 0.25f * ((a1.z + a1.w) + (b1.z + b1.w));
        *(float4*)(d1 + (size_t)(tY * 64 + ty * 4 + i) * 256 + tX * 64 + tx * 4) =
            *(float4*)s1v[i];
    }
    float s2v[2][2];
#pragma unroll
    for (int i = 0; i < 2; ++i) {
#pragma unroll
        for (int j = 0; j < 2; ++j)
            s2v[i][j] = 0.25f * ((s1v[2*i][2*j] + s1v[2*i][2*j+1]) +
                                 (s1v[2*i+1][2*j] + s1v[2*i+1][2*j+1]));
        *(float2*)(d2 + (size_t)(tY * 32 + ty * 2 + i) * 128 + tX * 32 + tx * 2) =
            *(float2*)s2v[i];
    }
    float s3 = 0.25f * ((s2v[0][0] + s2v[0][1]) + (s2v[1][0] + s2v[1][1]));
    d3[(size_t)(tY * 16 + ty) * 64 + tX * 16 + tx] = s3;
    // s4: 2x2 reduce across threads (lanes +-1, +-16 within wave)
    float v1 = s3 + __shfl_xor(s3, 1, 64);
    float v2 = v1 + __shfl_xor(v1, 16, 64);
    if ((ty & 1) == 0 && (tx & 1) == 0)
        d4[(size_t)(tY * 8 + (ty >> 1)) * 32 + tX * 8 + (tx >> 1)] = 0.25f * v2;
}

// ---------------- kernel B: ssim scales 1-4 (depend on pools) ----------------
__global__ __launch_bounds__(256) void k_ssim_rest(
        const float* __restrict__ p1, const float* __restrict__ t1,
        const float* __restrict__ p2, const float* __restrict__ t2,
        const float* __restrict__ p3, const float* __restrict__ t3,
        const float* __restrict__ p4, const float* __restrict__ t4,
        const float* __restrict__ k2d, double* __restrict__ accum) {
    int b   = blockIdx.x;
    int tid = threadIdx.x;
    if (b < 384)      ssim_scale(p1, t1, 256, 8, b,       1, b & 7, tid, k2d, accum);
    else if (b < 480) ssim_scale(p2, t2, 128, 7, b - 384, 2, b & 7, tid, k2d, accum);
    else if (b < 504) ssim_scale(p3, t3, 64,  6, b - 480, 3, b & 7, tid, k2d, accum);
    else              ssim_scale(p4, t4, 32,  5, b - 504, 4, b & 7, tid, k2d, accum);
}

// ---------------- finalize: weighted power product ----------------
__global__ void k_final(const double* __restrict__ accum, float* __restrict__ out) {
    if (threadIdx.x != 0 || blockIdx.x != 0) return;
    const double wts[5] = {0.0448, 0.2856, 0.3001, 0.2363, 0.1333};
    double ms = 1.0;
    int Hs = 512;
    for (int s = 0; s < 5; ++s) {
        double lt = 0.0, ct = 0.0;
        for (int k = 0; k < 8; ++k) {
            lt += accum[(s * 8 + k) * 2];
            ct += accum[(s * 8 + k) * 2 + 1];
        }
        double N  = 48.0 * (double)Hs * (double)Hs;
        double l  = lt / N;
        double cs = ct / N;
        if (cs < 1e-8) cs = 1e-8;
        if (s == 4) {
            if (l < 1e-8) l = 1e-8;
            ms *= pow(l, wts[s]) * pow(cs, wts[s]);
        } else {
            ms *= pow(cs, wts[s]);
        }
        Hs >>= 1;
    }
    out[0] = (float)ms;
}

extern "C" void kernel_launch(void* const* d_in, const int* in_sizes, int n_in,
                              void* d_out, int out_size, void* d_ws, size_t ws_size,
                              hipStream_t stream) {
    const float* pred = (const float*)d_in[0];
    const float* targ = (const float*)d_in[1];
    const float* kern = (const float*)d_in[2];
    float* out = (float*)d_out;

    char* ws = (char*)d_ws;
    double* accum = (double*)ws;             // 80 doubles (5 scales * 8 slots * 2)
    size_t off = 1024;
    float* p1 = (float*)(ws + off); off += (size_t)NP * 256 * 256 * 4;
    float* t1 = (float*)(ws + off); off += (size_t)NP * 256 * 256 * 4;
    float* p2 = (float*)(ws + off); off += (size_t)NP * 128 * 128 * 4;
    float* t2 = (float*)(ws + off); off += (size_t)NP * 128 * 128 * 4;
    float* p3 = (float*)(ws + off); off += (size_t)NP * 64 * 64 * 4;
    float* t3 = (float*)(ws + off); off += (size_t)NP * 64 * 64 * 4;
    float* p4 = (float*)(ws + off); off += (size_t)NP * 32 * 32 * 4;
    float* t4 = (float*)(ws + off); off += (size_t)NP * 32 * 32 * 4;

    hipMemsetAsync(accum, 0, 640, stream);
    k_main<<<3072, 256, 0, stream>>>(pred, targ, p1, t1, p2, t2, p3, t3, p4, t4, kern, accum);
    k_ssim_rest<<<510, 256, 0, stream>>>(p1, t1, p2, t2, p3, t3, p4, t4, kern, accum);
    k_final<<<1, 1, 0, stream>>>(accum, out);
}

// Round 8
// 230.988 us; speedup vs baseline: 2.4041x; 1.0268x over previous
//
#include <hip/hip_runtime.h>
#include <math.h>

#define NP 48   // 16 batch * 3 channels

typedef float v2f __attribute__((ext_vector_type(2)));

__device__ __forceinline__ float uniform_f(float v) {
    int i = __builtin_amdgcn_readfirstlane(__builtin_bit_cast(int, v));
    return __builtin_bit_cast(float, i);
}

// ---------------- fully-unrolled sliding-window core ----------------
// GT: block touches top edge (yb==0); GB: block touches bottom edge (yb+32==H).
// With full unroll, all row guards fold to compile-time step-index tests.
template<bool GT, bool GB>
__device__ __forceinline__ void ssim_loop(
        const float* __restrict__ pP, const float* __restrict__ pT, int H,
        const float* __restrict__ w,   // wave-uniform (SGPR)
        const float* __restrict__ wc,  // per-lane edge-zeroed weights
        float& lsum, float& csum)
{
    v2f wmu[11], we[11];
    float wpt[11];
    const float C1 = 1e-4f, C2 = 9e-4f;
#pragma unroll
    for (int s = 0; s < 42; ++s) {
        v2f a_mu = (v2f){0.f, 0.f};
        v2f a_e  = (v2f){0.f, 0.f};
        v2f a_pt = (v2f){0.f, 0.f};
        if ((!GT || s >= 5) && (!GB || s < 37)) {   // compile-time after unroll
#pragma unroll
            for (int j = 0; j < 11; ++j) {
                v2f pt2 = (v2f){pP[j], pT[j]};
                v2f wv  = (v2f){wc[j], wc[j]};      // splat -> VOP3P op_sel
                v2f wp2 = wv * pt2;
                v2f ptr2 = (v2f){pt2.y, pt2.x};     // swap -> VOP3P op_sel
                a_mu += wp2;
                a_e  += wp2 * pt2;
                a_pt += wp2 * ptr2;                 // halves: wp*t , wt*p
            }
        }
        wmu[s % 11] = a_mu;
        we[s % 11]  = a_e;
        wpt[s % 11] = a_pt.x + a_pt.y;              // = 2*sum(w p t)
        if (s >= 10) {                              // emit output row yb + s - 10
            v2f mu2 = (v2f){0.f, 0.f};
            v2f e2  = (v2f){0.f, 0.f};
            float ept = 0.f;
#pragma unroll
            for (int i = 0; i < 11; ++i) {
                const int sl = (s + 1 + i) % 11;    // compile-time
                v2f wi = (v2f){w[i], w[i]};         // SGPR broadcast
                mu2 += wi * wmu[sl];
                e2  += wi * we[sl];
                ept += w[i] * wpt[sl];
            }
            float m11 = mu2.x * mu2.x, m22 = mu2.y * mu2.y, m12 = mu2.x * mu2.y;
            float s1  = fmaxf(e2.x - m11, 0.f);
            float s2  = fmaxf(e2.y - m22, 0.f);
            float s12 = 0.5f * ept - m12;           // undo the 2x from packed pt
            lsum += (2.f * m12 + C1) * __builtin_amdgcn_rcpf(m11 + m22 + C1);
            csum += (2.f * s12 + C2) * __builtin_amdgcn_rcpf(s1 + s2 + C2);
        }
        pP += H; pT += H;
    }
}

// ---------------- per-scale wrapper: prep + template dispatch + reduce ----------------
__device__ __forceinline__ void ssim_scale(
        const float* __restrict__ P, const float* __restrict__ T,
        int H, int sh, int lb, int scale, int slotsel, int tid,
        const float* __restrict__ k2d, double* __restrict__ accum)
{
    // normalized 1D gaussian from center row of 2D kernel, pinned to SGPRs
    float w[11];
    {
        float s = 0.f;
#pragma unroll
        for (int i = 0; i < 11; ++i) s += k2d[55 + i];
        float inv = 1.0f / s;
#pragma unroll
        for (int i = 0; i < 11; ++i) w[i] = uniform_f(k2d[55 + i] * inv);
    }

    int blocksX = (NP << sh) >> 8;          // 48*H / 256
    int bxi = lb % blocksX;
    int by  = lb / blocksX;
    int g   = (bxi << 8) + tid;
    int pl  = g >> sh;
    int x   = g & (H - 1);
    int yb  = by * 32;

    // per-lane clamped window base + edge-zeroed weights
    int bcl = x - 5;
    bcl = bcl < 0 ? 0 : bcl;
    bcl = bcl > H - 11 ? H - 11 : bcl;
    int d = bcl - (x - 5);                  // in [-5, 5]; 0 for interior lanes
    float wc[11];
#pragma unroll
    for (int j = 0; j < 11; ++j) {
        int idx = j + d;
        float val = 0.f;
#pragma unroll
        for (int i = 0; i < 11; ++i) val = (idx == i) ? w[i] : val;
        wc[j] = val;
    }

    const float* pP = P + (size_t)pl * H * H + (ptrdiff_t)(yb - 5) * H + bcl;
    const float* pT = T + (size_t)pl * H * H + (ptrdiff_t)(yb - 5) * H + bcl;

    float lsum = 0.f, csum = 0.f;
    bool gt = (yb == 0);
    bool gb = (yb + 32 == H);
    if (gt) {
        if (gb) ssim_loop<true, true >(pP, pT, H, w, wc, lsum, csum);
        else    ssim_loop<true, false>(pP, pT, H, w, wc, lsum, csum);
    } else {
        if (gb) ssim_loop<false, true >(pP, pT, H, w, wc, lsum, csum);
        else    ssim_loop<false, false>(pP, pT, H, w, wc, lsum, csum);
    }

    // wave shuffle reduce then cross-wave via LDS
#pragma unroll
    for (int o = 32; o > 0; o >>= 1) {
        lsum += __shfl_down(lsum, o, 64);
        csum += __shfl_down(csum, o, 64);
    }
    __shared__ float red[8];
    int wv = tid >> 6;
    if ((tid & 63) == 0) { red[2 * wv] = lsum; red[2 * wv + 1] = csum; }
    __syncthreads();
    if (tid == 0) {
        int slot = (scale * 8 + slotsel) * 2;
        atomicAdd(&accum[slot],     (double)(red[0] + red[2] + red[4] + red[6]));
        atomicAdd(&accum[slot + 1], (double)(red[1] + red[3] + red[5] + red[7]));
    }
}

// ---------------- kernel A: pool blocks [0,1536) || ssim scale-0 blocks [1536,3072) ----------------
__global__ __launch_bounds__(256) void k_main(
        const float* __restrict__ pred, const float* __restrict__ targ,
        float* __restrict__ p1, float* __restrict__ t1,
        float* __restrict__ p2, float* __restrict__ t2,
        float* __restrict__ p3, float* __restrict__ t3,
        float* __restrict__ p4, float* __restrict__ t4,
        const float* __restrict__ k2d, double* __restrict__ accum) {
    int b   = blockIdx.x;
    int tid = threadIdx.x;
    if (b >= 1536) {
        ssim_scale(pred, targ, 512, 9, b - 1536, 0, b & 7, tid, k2d, accum);
        return;
    }
    // ---- pool path: 64x64 s1 tile; all scales from s0 (mean of means) ----
    int pi   = b >> 4;          // 0..95 plane-image
    int tile = b & 15;          // 4x4 tiles over the 256x256 s1 plane
    int pls  = pi < 48 ? pi : pi - 48;
    const float* src = (pi < 48 ? pred : targ) + (size_t)pls * 512 * 512;
    float* d1 = (pi < 48 ? p1 : t1) + (size_t)pls * 256 * 256;
    float* d2 = (pi < 48 ? p2 : t2) + (size_t)pls * 128 * 128;
    float* d3 = (pi < 48 ? p3 : t3) + (size_t)pls * 64 * 64;
    float* d4 = (pi < 48 ? p4 : t4) + (size_t)pls * 32 * 32;
    int tY = tile >> 2, tX = tile & 3;
    int ty = tid >> 4, tx = tid & 15;
    int gy0 = tY * 128 + ty * 8, gx0 = tX * 128 + tx * 8;

    float s1v[4][4];
#pragma unroll
    for (int i = 0; i < 4; ++i) {
        const float* r0 = src + (size_t)(gy0 + 2 * i) * 512 + gx0;
        const float* r1 = r0 + 512;
        float4 a0 = *(const float4*)r0, a1 = *(const float4*)(r0 + 4);
        float4 b0 = *(const float4*)r1, b1 = *(const float4*)(r1 + 4);
        s1v[i][0] = 0.25f * ((a0.x + a0.y) + (b0.x + b0.y));
        s1v[i][1] = 0.25f * ((a0.z + a0.w) + (b0.z + b0.w));
        s1v[i][2] = 0.25f * ((a1.x + a1.y) + (b1.x + b1.y));
        s1v[i][3] = 0.25f * ((a1.z + a1.w) + (b1.z + b1.w));
        *(float4*)(d1 + (size_t)(tY * 64 + ty * 4 + i) * 256 + tX * 64 + tx * 4) =
            *(float4*)s1v[i];
    }
    float s2v[2][2];
#pragma unroll
    for (int i = 0; i < 2; ++i) {
#pragma unroll
        for (int j = 0; j < 2; ++j)
            s2v[i][j] = 0.25f * ((s1v[2*i][2*j] + s1v[2*i][2*j+1]) +
                                 (s1v[2*i+1][2*j] + s1v[2*i+1][2*j+1]));
        *(float2*)(d2 + (size_t)(tY * 32 + ty * 2 + i) * 128 + tX * 32 + tx * 2) =
            *(float2*)s2v[i];
    }
    float s3 = 0.25f * ((s2v[0][0] + s2v[0][1]) + (s2v[1][0] + s2v[1][1]));
    d3[(size_t)(tY * 16 + ty) * 64 + tX * 16 + tx] = s3;
    float v1 = s3 + __shfl_xor(s3, 1, 64);
    float v2 = v1 + __shfl_xor(v1, 16, 64);
    if ((ty & 1) == 0 && (tx & 1) == 0)
        d4[(size_t)(tY * 8 + (ty >> 1)) * 32 + tX * 8 + (tx >> 1)] = 0.25f * v2;
}

// ---------------- kernel B: ssim scales 1-4 (depend on pools) ----------------
__global__ __launch_bounds__(256) void k_ssim_rest(
        const float* __restrict__ p1, const float* __restrict__ t1,
        const float* __restrict__ p2, const float* __restrict__ t2,
        const float* __restrict__ p3, const float* __restrict__ t3,
        const float* __restrict__ p4, const float* __restrict__ t4,
        const float* __restrict__ k2d, double* __restrict__ accum) {
    int b   = blockIdx.x;
    int tid = threadIdx.x;
    if (b < 384)      ssim_scale(p1, t1, 256, 8, b,       1, b & 7, tid, k2d, accum);
    else if (b < 480) ssim_scale(p2, t2, 128, 7, b - 384, 2, b & 7, tid, k2d, accum);
    else if (b < 504) ssim_scale(p3, t3, 64,  6, b - 480, 3, b & 7, tid, k2d, accum);
    else              ssim_scale(p4, t4, 32,  5, b - 504, 4, b & 7, tid, k2d, accum);
}

// ---------------- finalize: weighted power product (float path) ----------------
__global__ void k_final(const double* __restrict__ accum, float* __restrict__ out) {
    if (threadIdx.x != 0 || blockIdx.x != 0) return;
    const float wts[5] = {0.0448f, 0.2856f, 0.3001f, 0.2363f, 0.1333f};
    float ms = 1.0f;
    int Hs = 512;
    for (int s = 0; s < 5; ++s) {
        double lt = 0.0, ct = 0.0;
        for (int k = 0; k < 8; ++k) {
            lt += accum[(s * 8 + k) * 2];
            ct += accum[(s * 8 + k) * 2 + 1];
        }
        float N  = 48.0f * (float)Hs * (float)Hs;
        float l  = (float)lt / N;
        float cs = (float)ct / N;
        cs = fmaxf(cs, 1e-8f);
        if (s == 4) {
            l = fmaxf(l, 1e-8f);
            ms *= powf(l, wts[s]) * powf(cs, wts[s]);
        } else {
            ms *= powf(cs, wts[s]);
        }
        Hs >>= 1;
    }
    out[0] = ms;
}

extern "C" void kernel_launch(void* const* d_in, const int* in_sizes, int n_in,
                              void* d_out, int out_size, void* d_ws, size_t ws_size,
                              hipStream_t stream) {
    const float* pred = (const float*)d_in[0];
    const float* targ = (const float*)d_in[1];
    const float* kern = (const float*)d_in[2];
    float* out = (float*)d_out;

    char* ws = (char*)d_ws;
    double* accum = (double*)ws;             // 80 doubles (5 scales * 8 slots * 2)
    size_t off = 1024;
    float* p1 = (float*)(ws + off); off += (size_t)NP * 256 * 256 * 4;
    float* t1 = (float*)(ws + off); off += (size_t)NP * 256 * 256 * 4;
    float* p2 = (float*)(ws + off); off += (size_t)NP * 128 * 128 * 4;
    float* t2 = (float*)(ws + off); off += (size_t)NP * 128 * 128 * 4;
    float* p3 = (float*)(ws + off); off += (size_t)NP * 64 * 64 * 4;
    float* t3 = (float*)(ws + off); off += (size_t)NP * 64 * 64 * 4;
    float* p4 = (float*)(ws + off); off += (size_t)NP * 32 * 32 * 4;
    float* t4 = (float*)(ws + off); off += (size_t)NP * 32 * 32 * 4;

    hipMemsetAsync(accum, 0, 640, stream);
    k_main<<<3072, 256, 0, stream>>>(pred, targ, p1, t1, p2, t2, p3, t3, p4, t4, kern, accum);
    k_ssim_rest<<<510, 256, 0, stream>>>(p1, t1, p2, t2, p3, t3, p4, t4, kern, accum);
    k_final<<<1, 1, 0, stream>>>(accum, out);
}